// Round 5
// baseline (341.131 us; speedup 1.0000x reference)
//
#include <hip/hip_runtime.h>
#include <stdint.h>
#include <math.h>

#define EPSV   1e-5f
#define BATCH  4096
#define GDIM   4096
#define NFEAT  1536   // 64 terms * 24
#define NBLK   256    // tail grid: 1 block/CU, co-resident by construction

typedef __attribute__((ext_vector_type(8))) short bf16x8;
typedef __attribute__((ext_vector_type(4))) float f32x4;
typedef __attribute__((ext_vector_type(4))) uint32_t u32x4;

__device__ __forceinline__ uint32_t pkbf(float x, float y) {
    uint32_t a = __float_as_uint(x) + 0x8000u;
    uint32_t b = __float_as_uint(y) + 0x8000u;
    return __builtin_amdgcn_perm(b, a, 0x07060302u);
}
__device__ __forceinline__ uint16_t f2bf(float f) {
    return (uint16_t)((__float_as_uint(f) + 0x8000u) >> 16);
}
__device__ __forceinline__ void glds16(const uint16_t* g, short* l) {
    __builtin_amdgcn_global_load_lds(
        (const __attribute__((address_space(1))) void*)g,
        (__attribute__((address_space(3))) void*)l, 16, 0, 0);
}
// device-scope coherent read of a stat cell (dodges per-XCD L2 staleness)
__device__ __forceinline__ float aread(float* p) { return atomicAdd(p, 0.0f); }

__device__ __forceinline__ void grid_barrier(int* bar, int target) {
    __syncthreads();
    if (threadIdx.x == 0) {
        __threadfence();
        atomicAdd(bar, 1);
        while (__hip_atomic_load(bar, __ATOMIC_ACQUIRE, __HIP_MEMORY_SCOPE_AGENT) < target)
            __builtin_amdgcn_s_sleep(2);
    }
    __syncthreads();
}

// ---------------------------------------------------------------------------
// Convert x + gene_W f32 -> bf16 (8 f32/thread); block 0 zeroes stats+barrier.
// ---------------------------------------------------------------------------
__global__ __launch_bounds__(256) void cvt_bf16(
    const float* __restrict__ x, const float* __restrict__ w,
    uint16_t* __restrict__ xb, uint16_t* __restrict__ wb,
    float* __restrict__ stats)
{
    if (blockIdx.x == 0)
        for (int j = threadIdx.x; j < 1040; j += 256) stats[j] = 0.f;
    const size_t NX = (size_t)BATCH * GDIM / 8;
    size_t i = (size_t)blockIdx.x * 256 + threadIdx.x;
    const float* src; uint16_t* dst;
    if (i < NX) { src = x + i * 8; dst = xb + i * 8; }
    else        { size_t j = i - NX; src = w + j * 8; dst = wb + j * 8; }
    f32x4 v0 = *(const f32x4*)src;
    f32x4 v1 = *(const f32x4*)(src + 4);
    u32x4 p = (u32x4){pkbf(v0[0],v0[1]), pkbf(v0[2],v0[3]),
                      pkbf(v1[0],v1[1]), pkbf(v1[2],v1[3])};
    *(u32x4*)dst = p;
}

// ---------------------------------------------------------------------------
// m97-style GEMM (unchanged from R4): glds16 staging, 128x128 tile, BK=32,
// split-K z=2: z=0 -> f32 C0 (+bias), z=1 -> bf16 C1.
// ---------------------------------------------------------------------------
__global__ __launch_bounds__(256) void gemm_glds(
    const uint16_t* __restrict__ A, const uint16_t* __restrict__ Bw,
    const float* __restrict__ bias, float* __restrict__ C0,
    uint16_t* __restrict__ C1, int KC)
{
    const int N = NFEAT, K = GDIM;
    __shared__ short sA[128 * 32];
    __shared__ short sB[128 * 32];
    const int tid  = threadIdx.x;
    const int m0   = blockIdx.y * 128, n0 = blockIdx.x * 128;
    const int kbase = blockIdx.z * KC;
    const int wave = tid >> 6, lane = tid & 63;
    const int wm   = (wave & 1) << 6, wn = (wave >> 1) << 6;
    const int lm   = lane & 15, quad = lane >> 4;

    f32x4 acc[4][4];
#pragma unroll
    for (int i = 0; i < 4; ++i)
#pragma unroll
        for (int j = 0; j < 4; ++j) acc[i][j] = (f32x4){0.f, 0.f, 0.f, 0.f};

    const int r0  = tid >> 2;
    const int c0e = (tid & 3) << 3;
    const uint16_t* gA = A  + (size_t)(m0 + r0) * K + kbase + c0e;
    const uint16_t* gB = Bw + (size_t)(n0 + r0) * K + kbase + c0e;
    short* la0 = &sA[tid * 8];
    short* la1 = &sA[2048 + tid * 8];
    short* lb0 = &sB[tid * 8];
    short* lb1 = &sB[2048 + tid * 8];
    const size_t rowskip = (size_t)64 * K;

    for (int k0 = 0; k0 < KC; k0 += 32) {
        __syncthreads();
        glds16(gA + k0,            la0);
        glds16(gA + rowskip + k0,  la1);
        glds16(gB + k0,            lb0);
        glds16(gB + rowskip + k0,  lb1);
        __syncthreads();
        bf16x8 af[4], bfr[4];
#pragma unroll
        for (int m = 0; m < 4; ++m)
            af[m]  = *(const bf16x8*)&sA[(wm + m * 16 + lm) * 32 + quad * 8];
#pragma unroll
        for (int n = 0; n < 4; ++n)
            bfr[n] = *(const bf16x8*)&sB[(wn + n * 16 + lm) * 32 + quad * 8];
#pragma unroll
        for (int m = 0; m < 4; ++m)
#pragma unroll
            for (int n = 0; n < 4; ++n)
                acc[m][n] = __builtin_amdgcn_mfma_f32_16x16x32_bf16(
                    af[m], bfr[n], acc[m][n], 0, 0, 0);
    }
    if (blockIdx.z == 0) {
#pragma unroll
        for (int n = 0; n < 4; ++n) {
            const int col = n0 + wn + n * 16 + lm;
            const float bv = bias[col];
#pragma unroll
            for (int m = 0; m < 4; ++m) {
                const int row = m0 + wm + m * 16 + (quad << 2);
                float* cp = C0 + (size_t)row * N + col;
#pragma unroll
                for (int r = 0; r < 4; ++r) cp[(size_t)r * N] = acc[m][n][r] + bv;
            }
        }
    } else {
#pragma unroll
        for (int n = 0; n < 4; ++n) {
            const int col = n0 + wn + n * 16 + lm;
#pragma unroll
            for (int m = 0; m < 4; ++m) {
                const int row = m0 + wm + m * 16 + (quad << 2);
                uint16_t* cp = C1 + (size_t)row * N + col;
#pragma unroll
                for (int r = 0; r < 4; ++r) cp[(size_t)r * N] = f2bf(acc[m][n][r]);
            }
        }
    }
}

// ---------------------------------------------------------------------------
// Fused tail: L0+L1+L2+L3+final in one dispatch. 256 blocks x 256 threads,
// 16 rows/block held in LDS; batch-wide BN stats via global atomics + manual
// grid barriers (1 block/CU -> co-resident).
// ---------------------------------------------------------------------------
__global__ __launch_bounds__(256) void tail_fused(
    const float* __restrict__ p0, const uint16_t* __restrict__ p1b,
    const float* __restrict__ term_W, const float* __restrict__ term_b,
    const float* __restrict__ bn_g, const float* __restrict__ bn_b,
    const float* __restrict__ a1W, const float* __restrict__ a1b,
    const float* __restrict__ a2W, const float* __restrict__ a2b,
    const float* __restrict__ fW, const float* __restrict__ fb,
    const float* __restrict__ fbn_g, const float* __restrict__ fbn_b,
    const float* __restrict__ fxW, const float* __restrict__ fxb,
    const float* __restrict__ foW, const float* __restrict__ fob,
    float* __restrict__ stats, float* __restrict__ out)
{
    float* st0 = stats;            // 384+384
    float* st1 = stats + 768;      // 96+96
    float* st2 = stats + 960;      // 24+24
    float* st3 = stats + 1008;     // 6+6
    float* fst = stats + 1020;     // 6+6
    int*   bar = (int*)(stats + 1032);

    __shared__ float Wl0[144 * 64], tbl0[6 * 64];
    __shared__ float Wl1[144 * 16], tbl1[6 * 16];
    __shared__ float Wl2[144 * 4],  tbl2[6 * 4];
    __shared__ float Wl3[144],      tbl3[6];
    __shared__ float z0L[16 * 385];          // padded stride
    __shared__ float z1L[16 * 97];
    __shared__ float z2L[16 * 25];
    __shared__ float z3L[16 * 7];
    __shared__ float fL [16 * 6];
    __shared__ float aAb[384], aCb[384];
    __shared__ float a1wb[384], a1bb[64], a2wb[64], a2bb[64];
    __shared__ float ps[1536], pq[1536];
    __shared__ float r12[12], a3L[6], c3L[6], avL[6], cvL[6];

    const int tid = threadIdx.x;
    const int rbase = blockIdx.x * 16;
    const float invB = 1.0f / BATCH;

    // ---- preload all level weights/biases ----
    for (int idx = tid; idx < 144 * 64; idx += 256) {
        int t = idx / 144, fh = idx - t * 144;
        Wl0[fh * 64 + t] = term_W[t * 144 + fh];
    }
    for (int idx = tid; idx < 144 * 16; idx += 256) {
        int t = idx / 144, fh = idx - t * 144;
        Wl1[fh * 16 + t] = term_W[(64 + t) * 144 + fh];
    }
    for (int idx = tid; idx < 144 * 4; idx += 256) {
        int t = idx / 144, fh = idx - t * 144;
        Wl2[fh * 4 + t] = term_W[(80 + t) * 144 + fh];
    }
    for (int idx = tid; idx < 144; idx += 256) Wl3[idx] = term_W[84 * 144 + idx];
    for (int idx = tid; idx < 384; idx += 256) {
        int t = idx / 6, h = idx - t * 6;
        tbl0[h * 64 + t] = term_b[t * 6 + h];
    }
    for (int idx = tid; idx < 96; idx += 256) {
        int t = idx / 6, h = idx - t * 6;
        tbl1[h * 16 + t] = term_b[(64 + t) * 6 + h];
    }
    if (tid < 24) { int t = tid / 6, h = tid - t * 6; tbl2[h * 4 + t] = term_b[(80 + t) * 6 + h]; }
    if (tid < 6)  tbl3[tid] = term_b[84 * 6 + tid];
    __syncthreads();

    // ================= Stage L0: h_in -> z0 (LDS) + st0 =================
    {
        const int term = tid & 63, grp = tid >> 6;    // 4 row-groups
        float s6[6], q6[6];
#pragma unroll
        for (int h = 0; h < 6; ++h) { s6[h] = 0.f; q6[h] = 0.f; }
        for (int it = 0; it < 4; ++it) {
            const int rl = it * 4 + grp;
            const int r  = rbase + rl;
            const float* inrow = p0 + (size_t)r * NFEAT + term * 24;
            float hv[24];
#pragma unroll
            for (int i4 = 0; i4 < 6; ++i4) {
                f32x4 v = *(const f32x4*)(inrow + 4 * i4);
                hv[4*i4+0] = v[0]; hv[4*i4+1] = v[1];
                hv[4*i4+2] = v[2]; hv[4*i4+3] = v[3];
            }
            const uint32_t* p2 = (const uint32_t*)(p1b + (size_t)r * NFEAT + term * 24);
#pragma unroll
            for (int i = 0; i < 12; ++i) {
                uint32_t u = p2[i];
                hv[2*i]   += __uint_as_float(u << 16);
                hv[2*i+1] += __uint_as_float(u & 0xffff0000u);
            }
            float za[6];
#pragma unroll
            for (int h = 0; h < 6; ++h) za[h] = tbl0[h * 64 + term];
#pragma unroll
            for (int i = 0; i < 24; ++i) {
                const float xv = hv[i];
#pragma unroll
                for (int h = 0; h < 6; ++h) za[h] += xv * Wl0[(h * 24 + i) * 64 + term];
            }
#pragma unroll
            for (int h = 0; h < 6; ++h) {
                float z = tanhf(za[h]);
                z0L[rl * 385 + term * 6 + h] = z;
                s6[h] += z; q6[h] += z * z;
            }
        }
#pragma unroll
        for (int h = 0; h < 6; ++h) {
            ps[grp * 384 + term * 6 + h] = s6[h];
            pq[grp * 384 + term * 6 + h] = q6[h];
        }
        __syncthreads();
        for (int f = tid; f < 384; f += 256) {
            float s = 0.f, q = 0.f;
#pragma unroll
            for (int g = 0; g < 4; ++g) { s += ps[g * 384 + f]; q += pq[g * 384 + f]; }
            atomicAdd(&st0[f], s);
            atomicAdd(&st0[384 + f], q);
        }
    }
    grid_barrier(bar, NBLK * 1);

    // ================= Stage L1: BN0 + aux0..63 + z1 + st1 =================
    {
        for (int j = tid; j < 384; j += 256) {
            float s = aread(&st0[j]), q = aread(&st0[384 + j]);
            float mu = s * invB, var = q * invB - mu * mu;
            float a = rsqrtf(var + EPSV) * bn_g[j];
            int t = j / 24, i = j - t * 24;
            aAb[i * 16 + t] = a;
            aCb[i * 16 + t] = bn_b[j] - mu * a;
        }
        for (int idx = tid; idx < 384; idx += 256) {
            int t = idx / 6, h = idx - t * 6;
            a1wb[h * 64 + t] = a1W[t * 6 + h];
        }
        if (tid < 64) { a1bb[tid] = a1b[tid]; a2wb[tid] = a2W[tid]; a2bb[tid] = a2b[tid]; }
        __syncthreads();

        const int term = tid & 15, grp = tid >> 4;    // 16 rows
        const int r = rbase + grp;
        float hv[24];
#pragma unroll
        for (int i = 0; i < 24; ++i)
            hv[i] = z0L[grp * 385 + term * 24 + i] * aAb[i * 16 + term] + aCb[i * 16 + term];
#pragma unroll
        for (int s = 0; s < 4; ++s) {
            const int tp = term * 4 + s;
            float acc = a1bb[tp];
#pragma unroll
            for (int h2 = 0; h2 < 6; ++h2) acc += hv[s * 6 + h2] * a1wb[h2 * 64 + tp];
            out[(size_t)r * 86 + tp] = tanhf(acc) * a2wb[tp] + a2bb[tp];
        }
        float za[6];
#pragma unroll
        for (int h = 0; h < 6; ++h) za[h] = tbl1[h * 16 + term];
#pragma unroll
        for (int i = 0; i < 24; ++i) {
            const float xv = hv[i];
#pragma unroll
            for (int h = 0; h < 6; ++h) za[h] += xv * Wl1[(h * 24 + i) * 16 + term];
        }
#pragma unroll
        for (int h = 0; h < 6; ++h) {
            float z = tanhf(za[h]);
            z1L[grp * 97 + term * 6 + h] = z;
            ps[grp * 96 + term * 6 + h] = z;
            pq[grp * 96 + term * 6 + h] = z * z;
        }
        __syncthreads();
        for (int f = tid; f < 96; f += 256) {
            float s = 0.f, q = 0.f;
#pragma unroll
            for (int g = 0; g < 16; ++g) { s += ps[g * 96 + f]; q += pq[g * 96 + f]; }
            atomicAdd(&st1[f], s);
            atomicAdd(&st1[96 + f], q);
        }
    }
    grid_barrier(bar, NBLK * 2);

    // ================= Stage L2: BN1 + aux64..79 + z2 + st2 =================
    {
        for (int j = tid; j < 96; j += 256) {
            float s = aread(&st1[j]), q = aread(&st1[96 + j]);
            float mu = s * invB, var = q * invB - mu * mu;
            float a = rsqrtf(var + EPSV) * bn_g[64 * 6 + j];
            int t = j / 24, i = j - t * 24;
            aAb[i * 4 + t] = a;
            aCb[i * 4 + t] = bn_b[64 * 6 + j] - mu * a;
        }
        for (int idx = tid; idx < 96; idx += 256) {
            int t = idx / 6, h = idx - t * 6;
            a1wb[h * 16 + t] = a1W[(64 + t) * 6 + h];
        }
        if (tid < 16) { a1bb[tid] = a1b[64 + tid]; a2wb[tid] = a2W[64 + tid]; a2bb[tid] = a2b[64 + tid]; }
        __syncthreads();

        const int term = tid & 3, row = tid >> 2;     // rows 0..63, 16 valid
        if (row < 16) {
            const int r = rbase + row;
            float hv[24];
#pragma unroll
            for (int i = 0; i < 24; ++i)
                hv[i] = z1L[row * 97 + term * 24 + i] * aAb[i * 4 + term] + aCb[i * 4 + term];
#pragma unroll
            for (int s = 0; s < 4; ++s) {
                const int tp = term * 4 + s;
                float acc = a1bb[tp];
#pragma unroll
                for (int h2 = 0; h2 < 6; ++h2) acc += hv[s * 6 + h2] * a1wb[h2 * 16 + tp];
                out[(size_t)r * 86 + 64 + tp] = tanhf(acc) * a2wb[tp] + a2bb[tp];
            }
            float za[6];
#pragma unroll
            for (int h = 0; h < 6; ++h) za[h] = tbl2[h * 4 + term];
#pragma unroll
            for (int i = 0; i < 24; ++i) {
                const float xv = hv[i];
#pragma unroll
                for (int h = 0; h < 6; ++h) za[h] += xv * Wl2[(h * 24 + i) * 4 + term];
            }
#pragma unroll
            for (int h = 0; h < 6; ++h) {
                float z = tanhf(za[h]);
                z2L[row * 25 + term * 6 + h] = z;
                ps[row * 24 + term * 6 + h] = z;
                pq[row * 24 + term * 6 + h] = z * z;
            }
        }
        __syncthreads();
        if (tid < 24) {
            float s = 0.f, q = 0.f;
#pragma unroll
            for (int g = 0; g < 16; ++g) { s += ps[g * 24 + tid]; q += pq[g * 24 + tid]; }
            atomicAdd(&st2[tid], s);
            atomicAdd(&st2[24 + tid], q);
        }
    }
    grid_barrier(bar, NBLK * 3);

    // ================= Stage L3: BN2 + aux80..83 + z3 + st3 =================
    {
        if (tid < 24) {
            float s = aread(&st2[tid]), q = aread(&st2[24 + tid]);
            float mu = s * invB, var = q * invB - mu * mu;
            float a = rsqrtf(var + EPSV) * bn_g[80 * 6 + tid];
            aAb[tid] = a;
            aCb[tid] = bn_b[80 * 6 + tid] - mu * a;
        }
        if (tid < 24) { int t = tid / 6, h = tid - t * 6; a1wb[h * 4 + t] = a1W[(80 + t) * 6 + h]; }
        if (tid < 4) { a1bb[tid] = a1b[80 + tid]; a2wb[tid] = a2W[80 + tid]; a2bb[tid] = a2b[80 + tid]; }
        __syncthreads();

        const int row = tid;                          // 16 valid
        if (row < 16) {
            const int r = rbase + row;
            float hv[24];
#pragma unroll
            for (int i = 0; i < 24; ++i)
                hv[i] = z2L[row * 25 + i] * aAb[i] + aCb[i];
#pragma unroll
            for (int s = 0; s < 4; ++s) {
                float acc = a1bb[s];
#pragma unroll
                for (int h2 = 0; h2 < 6; ++h2) acc += hv[s * 6 + h2] * a1wb[h2 * 4 + s];
                out[(size_t)r * 86 + 80 + s] = tanhf(acc) * a2wb[s] + a2bb[s];
            }
            float za[6];
#pragma unroll
            for (int h = 0; h < 6; ++h) za[h] = tbl3[h];
#pragma unroll
            for (int i = 0; i < 24; ++i) {
                const float xv = hv[i];
#pragma unroll
                for (int h = 0; h < 6; ++h) za[h] += xv * Wl3[h * 24 + i];
            }
#pragma unroll
            for (int h = 0; h < 6; ++h) {
                float z = tanhf(za[h]);
                z3L[row * 7 + h] = z;
                ps[row * 6 + h] = z;
                pq[row * 6 + h] = z * z;
            }
        }
        __syncthreads();
        if (tid < 6) {
            float s = 0.f, q = 0.f;
#pragma unroll
            for (int g = 0; g < 16; ++g) { s += ps[g * 6 + tid]; q += pq[g * 6 + tid]; }
            atomicAdd(&st3[tid], s);
            atomicAdd(&st3[6 + tid], q);
        }
    }
    grid_barrier(bar, NBLK * 4);

    // ================= Final pass 1: BN3 + aux84 + f + fstat =================
    {
        if (tid < 12) r12[tid] = aread(&st3[tid]);
        __syncthreads();
        if (tid < 6) {
            float mu = r12[tid] * invB, var = r12[6 + tid] * invB - mu * mu;
            float a = rsqrtf(var + EPSV) * bn_g[84 * 6 + tid];
            a3L[tid] = a;
            c3L[tid] = bn_b[84 * 6 + tid] - mu * a;
        }
        __syncthreads();
        const int row = tid;
        if (row < 16) {
            const int r = rbase + row;
            float h[6];
#pragma unroll
            for (int j = 0; j < 6; ++j) h[j] = z3L[row * 7 + j] * a3L[j] + c3L[j];
            float acc = a1b[84];
#pragma unroll
            for (int j = 0; j < 6; ++j) acc += h[j] * a1W[84 * 6 + j];
            out[(size_t)r * 86 + 84] = tanhf(acc) * a2W[84] + a2b[84];
#pragma unroll
            for (int j = 0; j < 6; ++j) {
                float s = fb[j];
#pragma unroll
                for (int k = 0; k < 6; ++k) s += h[k] * fW[j * 6 + k];
                float f = tanhf(s);
                fL[row * 6 + j] = f;
                ps[row * 6 + j] = f;
                pq[row * 6 + j] = f * f;
            }
        }
        __syncthreads();
        if (tid < 6) {
            float s = 0.f, q = 0.f;
#pragma unroll
            for (int g = 0; g < 16; ++g) { s += ps[g * 6 + tid]; q += pq[g * 6 + tid]; }
            atomicAdd(&fst[tid], s);
            atomicAdd(&fst[6 + tid], q);
        }
    }
    grid_barrier(bar, NBLK * 5);

    // ================= Final pass 2: fbn + pred (col 85) =================
    {
        if (tid < 12) r12[tid] = aread(&fst[tid]);
        __syncthreads();
        if (tid < 6) {
            float mu = r12[tid] * invB, var = r12[6 + tid] * invB - mu * mu;
            float a = rsqrtf(var + EPSV) * fbn_g[tid];
            avL[tid] = a;
            cvL[tid] = fbn_b[tid] - mu * a;
        }
        __syncthreads();
        const int row = tid;
        if (row < 16) {
            const int r = rbase + row;
            float acc = fxb[0];
#pragma unroll
            for (int j = 0; j < 6; ++j)
                acc += (fL[row * 6 + j] * avL[j] + cvL[j]) * fxW[j];
            float pre = tanhf(acc) * foW[0] + fob[0];
            out[(size_t)r * 86 + 85] = 1.0f / (1.0f + expf(-pre));
        }
    }
}

// ---------------------------------------------------------------------------
extern "C" void kernel_launch(void* const* d_in, const int* in_sizes, int n_in,
                              void* d_out, int out_size, void* d_ws, size_t ws_size,
                              hipStream_t stream)
{
    const float* x      = (const float*)d_in[0];
    const float* gene_W = (const float*)d_in[1];
    const float* gene_b = (const float*)d_in[2];
    const float* term_W = (const float*)d_in[3];
    const float* term_b = (const float*)d_in[4];
    const float* bn_g   = (const float*)d_in[5];
    const float* bn_b   = (const float*)d_in[6];
    const float* a1W    = (const float*)d_in[7];
    const float* a1b    = (const float*)d_in[8];
    const float* a2W    = (const float*)d_in[9];
    const float* a2b    = (const float*)d_in[10];
    const float* fW     = (const float*)d_in[11];
    const float* fb     = (const float*)d_in[12];
    const float* fbn_g  = (const float*)d_in[13];
    const float* fbn_b  = (const float*)d_in[14];
    const float* fxW    = (const float*)d_in[15];
    const float* fxb    = (const float*)d_in[16];
    const float* foW    = (const float*)d_in[17];
    const float* fob    = (const float*)d_in[18];
    float* out = (float*)d_out;

    const size_t XB  = 33554432;   // x bf16
    const size_t WBS = 12582912;   // gene_W bf16
    const size_t P0  = 25165824;   // f32 partial
    const size_t P1B = 12582912;   // bf16 partial

    char* ws = (char*)d_ws;
    uint16_t* xbuf = (uint16_t*)ws;
    uint16_t* wbuf = (uint16_t*)(ws + XB);
    float*    p0   = (float*)(ws + XB + WBS);
    uint16_t* p1b  = (uint16_t*)(ws + XB + WBS + P0);
    float*    stats = (float*)(ws + XB + WBS + P0 + P1B);  // 1040 f32

    cvt_bf16<<<11264, 256, 0, stream>>>(x, gene_W, xbuf, wbuf, stats);
    gemm_glds<<<dim3(12, 32, 2), 256, 0, stream>>>(xbuf, wbuf, gene_b, p0, p1b, GDIM / 2);
    tail_fused<<<NBLK, 256, 0, stream>>>(
        p0, p1b, term_W, term_b, bn_g, bn_b, a1W, a1b, a2W, a2b,
        fW, fb, fbn_g, fbn_b, fxW, fxb, foW, fob, stats, out);
}

// Round 7
// 320.722 us; speedup vs baseline: 1.0636x; 1.0636x over previous
//
#include <hip/hip_runtime.h>
#include <stdint.h>
#include <math.h>

#define EPSV   1e-5f
#define BATCH  4096
#define GDIM   4096
#define NFEAT  1536   // 64 terms * 24
#define NBLK   256    // tail grid: 1 block/CU, co-resident by construction

typedef __attribute__((ext_vector_type(8))) short bf16x8;
typedef __attribute__((ext_vector_type(4))) float f32x4;
typedef __attribute__((ext_vector_type(4))) uint32_t u32x4;

__device__ __forceinline__ uint32_t pkbf(float x, float y) {
    uint32_t a = __float_as_uint(x) + 0x8000u;
    uint32_t b = __float_as_uint(y) + 0x8000u;
    return __builtin_amdgcn_perm(b, a, 0x07060302u);
}
__device__ __forceinline__ uint16_t f2bf(float f) {
    return (uint16_t)((__float_as_uint(f) + 0x8000u) >> 16);
}
__device__ __forceinline__ void glds16(const uint16_t* g, short* l) {
    __builtin_amdgcn_global_load_lds(
        (const __attribute__((address_space(1))) void*)g,
        (__attribute__((address_space(3))) void*)l, 16, 0, 0);
}
// relaxed agent-scope f32 add: lands at LLC, coherent across XCDs
__device__ __forceinline__ void stat_add(float* p, float v) {
    __hip_atomic_fetch_add(p, v, __ATOMIC_RELAXED, __HIP_MEMORY_SCOPE_AGENT);
}

// Grid barrier: relaxed polling (no per-poll cache invalidate!), then ONE
// acquire-ordered load after the target is reached (single buffer_inv per
// block per barrier). Arrive = release fetch_add.
__device__ __forceinline__ void grid_barrier(int* bar, int target) {
    __syncthreads();
    if (threadIdx.x == 0) {
        __hip_atomic_fetch_add(bar, 1, __ATOMIC_RELEASE, __HIP_MEMORY_SCOPE_AGENT);
        while (__hip_atomic_load(bar, __ATOMIC_RELAXED, __HIP_MEMORY_SCOPE_AGENT) < target)
            __builtin_amdgcn_s_sleep(8);
        (void)__hip_atomic_load(bar, __ATOMIC_ACQUIRE, __HIP_MEMORY_SCOPE_AGENT);
    }
    __syncthreads();   // block-wide visibility through freshly-invalidated L1/L2
}

// ---------------------------------------------------------------------------
// Convert x + gene_W f32 -> bf16 (8 f32/thread); block 0 zeroes stats+barrier.
// ---------------------------------------------------------------------------
__global__ __launch_bounds__(256) void cvt_bf16(
    const float* __restrict__ x, const float* __restrict__ w,
    uint16_t* __restrict__ xb, uint16_t* __restrict__ wb,
    float* __restrict__ stats)
{
    if (blockIdx.x == 0)
        for (int j = threadIdx.x; j < 1040; j += 256) stats[j] = 0.f;
    const size_t NX = (size_t)BATCH * GDIM / 8;
    size_t i = (size_t)blockIdx.x * 256 + threadIdx.x;
    const float* src; uint16_t* dst;
    if (i < NX) { src = x + i * 8; dst = xb + i * 8; }
    else        { size_t j = i - NX; src = w + j * 8; dst = wb + j * 8; }
    f32x4 v0 = *(const f32x4*)src;
    f32x4 v1 = *(const f32x4*)(src + 4);
    u32x4 p = (u32x4){pkbf(v0[0],v0[1]), pkbf(v0[2],v0[3]),
                      pkbf(v1[0],v1[1]), pkbf(v1[2],v1[3])};
    *(u32x4*)dst = p;
}

// ---------------------------------------------------------------------------
// m97-style GEMM (unchanged): glds16 staging, 128x128 tile, BK=32,
// split-K z=2: z=0 -> f32 C0 (+bias), z=1 -> bf16 C1.
// ---------------------------------------------------------------------------
__global__ __launch_bounds__(256) void gemm_glds(
    const uint16_t* __restrict__ A, const uint16_t* __restrict__ Bw,
    const float* __restrict__ bias, float* __restrict__ C0,
    uint16_t* __restrict__ C1, int KC)
{
    const int N = NFEAT, K = GDIM;
    __shared__ short sA[128 * 32];
    __shared__ short sB[128 * 32];
    const int tid  = threadIdx.x;
    const int m0   = blockIdx.y * 128, n0 = blockIdx.x * 128;
    const int kbase = blockIdx.z * KC;
    const int wave = tid >> 6, lane = tid & 63;
    const int wm   = (wave & 1) << 6, wn = (wave >> 1) << 6;
    const int lm   = lane & 15, quad = lane >> 4;

    f32x4 acc[4][4];
#pragma unroll
    for (int i = 0; i < 4; ++i)
#pragma unroll
        for (int j = 0; j < 4; ++j) acc[i][j] = (f32x4){0.f, 0.f, 0.f, 0.f};

    const int r0  = tid >> 2;
    const int c0e = (tid & 3) << 3;
    const uint16_t* gA = A  + (size_t)(m0 + r0) * K + kbase + c0e;
    const uint16_t* gB = Bw + (size_t)(n0 + r0) * K + kbase + c0e;
    short* la0 = &sA[tid * 8];
    short* la1 = &sA[2048 + tid * 8];
    short* lb0 = &sB[tid * 8];
    short* lb1 = &sB[2048 + tid * 8];
    const size_t rowskip = (size_t)64 * K;

    for (int k0 = 0; k0 < KC; k0 += 32) {
        __syncthreads();
        glds16(gA + k0,            la0);
        glds16(gA + rowskip + k0,  la1);
        glds16(gB + k0,            lb0);
        glds16(gB + rowskip + k0,  lb1);
        __syncthreads();
        bf16x8 af[4], bfr[4];
#pragma unroll
        for (int m = 0; m < 4; ++m)
            af[m]  = *(const bf16x8*)&sA[(wm + m * 16 + lm) * 32 + quad * 8];
#pragma unroll
        for (int n = 0; n < 4; ++n)
            bfr[n] = *(const bf16x8*)&sB[(wn + n * 16 + lm) * 32 + quad * 8];
#pragma unroll
        for (int m = 0; m < 4; ++m)
#pragma unroll
            for (int n = 0; n < 4; ++n)
                acc[m][n] = __builtin_amdgcn_mfma_f32_16x16x32_bf16(
                    af[m], bfr[n], acc[m][n], 0, 0, 0);
    }
    if (blockIdx.z == 0) {
#pragma unroll
        for (int n = 0; n < 4; ++n) {
            const int col = n0 + wn + n * 16 + lm;
            const float bv = bias[col];
#pragma unroll
            for (int m = 0; m < 4; ++m) {
                const int row = m0 + wm + m * 16 + (quad << 2);
                float* cp = C0 + (size_t)row * N + col;
#pragma unroll
                for (int r = 0; r < 4; ++r) cp[(size_t)r * N] = acc[m][n][r] + bv;
            }
        }
    } else {
#pragma unroll
        for (int n = 0; n < 4; ++n) {
            const int col = n0 + wn + n * 16 + lm;
#pragma unroll
            for (int m = 0; m < 4; ++m) {
                const int row = m0 + wm + m * 16 + (quad << 2);
                uint16_t* cp = C1 + (size_t)row * N + col;
#pragma unroll
                for (int r = 0; r < 4; ++r) cp[(size_t)r * N] = f2bf(acc[m][n][r]);
            }
        }
    }
}

// ---------------------------------------------------------------------------
// Fused tail: L0+L1+L2+L3+final in one dispatch. 256 blocks x 256 threads,
// 16 rows/block in LDS; batch-wide BN stats via agent-scope atomics + cheap
// grid barriers (relaxed poll, single acquire load at the end).
// ---------------------------------------------------------------------------
__global__ __launch_bounds__(256) void tail_fused(
    const float* __restrict__ p0, const uint16_t* __restrict__ p1b,
    const float* __restrict__ term_W, const float* __restrict__ term_b,
    const float* __restrict__ bn_g, const float* __restrict__ bn_b,
    const float* __restrict__ a1W, const float* __restrict__ a1b,
    const float* __restrict__ a2W, const float* __restrict__ a2b,
    const float* __restrict__ fW, const float* __restrict__ fb,
    const float* __restrict__ fbn_g, const float* __restrict__ fbn_b,
    const float* __restrict__ fxW, const float* __restrict__ fxb,
    const float* __restrict__ foW, const float* __restrict__ fob,
    float* __restrict__ stats, float* __restrict__ out)
{
    float* st0 = stats;            // 384+384
    float* st1 = stats + 768;      // 96+96
    float* st2 = stats + 960;      // 24+24
    float* st3 = stats + 1008;     // 6+6
    float* fst = stats + 1020;     // 6+6
    int*   bar = (int*)(stats + 1032);

    __shared__ float Wl0[144 * 64], tbl0[6 * 64];
    __shared__ float Wl1[144 * 16], tbl1[6 * 16];
    __shared__ float Wl2[144 * 4],  tbl2[6 * 4];
    __shared__ float Wl3[144],      tbl3[6];
    __shared__ float z0L[16 * 385];          // padded stride
    __shared__ float z1L[16 * 97];
    __shared__ float z2L[16 * 25];
    __shared__ float z3L[16 * 7];
    __shared__ float fL [16 * 6];
    __shared__ float aAb[384], aCb[384];
    __shared__ float a1wb[384], a1bb[64], a2wb[64], a2bb[64];
    __shared__ float ps[1536], pq[1536];
    __shared__ float r12[12], a3L[6], c3L[6], avL[6], cvL[6];

    const int tid = threadIdx.x;
    const int rbase = blockIdx.x * 16;
    const float invB = 1.0f / BATCH;

    // ---- preload all level weights/biases ----
    for (int idx = tid; idx < 144 * 64; idx += 256) {
        int t = idx / 144, fh = idx - t * 144;
        Wl0[fh * 64 + t] = term_W[t * 144 + fh];
    }
    for (int idx = tid; idx < 144 * 16; idx += 256) {
        int t = idx / 144, fh = idx - t * 144;
        Wl1[fh * 16 + t] = term_W[(64 + t) * 144 + fh];
    }
    for (int idx = tid; idx < 144 * 4; idx += 256) {
        int t = idx / 144, fh = idx - t * 144;
        Wl2[fh * 4 + t] = term_W[(80 + t) * 144 + fh];
    }
    for (int idx = tid; idx < 144; idx += 256) Wl3[idx] = term_W[84 * 144 + idx];
    for (int idx = tid; idx < 384; idx += 256) {
        int t = idx / 6, h = idx - t * 6;
        tbl0[h * 64 + t] = term_b[t * 6 + h];
    }
    for (int idx = tid; idx < 96; idx += 256) {
        int t = idx / 6, h = idx - t * 6;
        tbl1[h * 16 + t] = term_b[(64 + t) * 6 + h];
    }
    if (tid < 24) { int t = tid / 6, h = tid - t * 6; tbl2[h * 4 + t] = term_b[(80 + t) * 6 + h]; }
    if (tid < 6)  tbl3[tid] = term_b[84 * 6 + tid];
    __syncthreads();

    // ================= Stage L0: h_in -> z0 (LDS) + st0 =================
    {
        const int term = tid & 63, grp = tid >> 6;    // 4 row-groups
        float s6[6], q6[6];
#pragma unroll
        for (int h = 0; h < 6; ++h) { s6[h] = 0.f; q6[h] = 0.f; }
        for (int it = 0; it < 4; ++it) {
            const int rl = it * 4 + grp;
            const int r  = rbase + rl;
            const float* inrow = p0 + (size_t)r * NFEAT + term * 24;
            float hv[24];
#pragma unroll
            for (int i4 = 0; i4 < 6; ++i4) {
                f32x4 v = *(const f32x4*)(inrow + 4 * i4);
                hv[4*i4+0] = v[0]; hv[4*i4+1] = v[1];
                hv[4*i4+2] = v[2]; hv[4*i4+3] = v[3];
            }
            const uint32_t* p2 = (const uint32_t*)(p1b + (size_t)r * NFEAT + term * 24);
#pragma unroll
            for (int i = 0; i < 12; ++i) {
                uint32_t u = p2[i];
                hv[2*i]   += __uint_as_float(u << 16);
                hv[2*i+1] += __uint_as_float(u & 0xffff0000u);
            }
            float za[6];
#pragma unroll
            for (int h = 0; h < 6; ++h) za[h] = tbl0[h * 64 + term];
#pragma unroll
            for (int i = 0; i < 24; ++i) {
                const float xv = hv[i];
#pragma unroll
                for (int h = 0; h < 6; ++h) za[h] += xv * Wl0[(h * 24 + i) * 64 + term];
            }
#pragma unroll
            for (int h = 0; h < 6; ++h) {
                float z = tanhf(za[h]);
                z0L[rl * 385 + term * 6 + h] = z;
                s6[h] += z; q6[h] += z * z;
            }
        }
#pragma unroll
        for (int h = 0; h < 6; ++h) {
            ps[grp * 384 + term * 6 + h] = s6[h];
            pq[grp * 384 + term * 6 + h] = q6[h];
        }
        __syncthreads();
        for (int f = tid; f < 384; f += 256) {
            float s = 0.f, q = 0.f;
#pragma unroll
            for (int g = 0; g < 4; ++g) { s += ps[g * 384 + f]; q += pq[g * 384 + f]; }
            stat_add(&st0[f], s);
            stat_add(&st0[384 + f], q);
        }
    }
    grid_barrier(bar, NBLK * 1);

    // ================= Stage L1: BN0 + aux0..63 + z1 + st1 =================
    {
        for (int j = tid; j < 384; j += 256) {
            float s = st0[j], q = st0[384 + j];
            float mu = s * invB, var = q * invB - mu * mu;
            float a = rsqrtf(var + EPSV) * bn_g[j];
            int t = j / 24, i = j - t * 24;
            aAb[i * 16 + t] = a;
            aCb[i * 16 + t] = bn_b[j] - mu * a;
        }
        for (int idx = tid; idx < 384; idx += 256) {
            int t = idx / 6, h = idx - t * 6;
            a1wb[h * 64 + t] = a1W[t * 6 + h];
        }
        if (tid < 64) { a1bb[tid] = a1b[tid]; a2wb[tid] = a2W[tid]; a2bb[tid] = a2b[tid]; }
        __syncthreads();

        const int term = tid & 15, grp = tid >> 4;    // 16 rows
        const int r = rbase + grp;
        float hv[24];
#pragma unroll
        for (int i = 0; i < 24; ++i)
            hv[i] = z0L[grp * 385 + term * 24 + i] * aAb[i * 16 + term] + aCb[i * 16 + term];
#pragma unroll
        for (int s = 0; s < 4; ++s) {
            const int tp = term * 4 + s;
            float acc = a1bb[tp];
#pragma unroll
            for (int h2 = 0; h2 < 6; ++h2) acc += hv[s * 6 + h2] * a1wb[h2 * 64 + tp];
            out[(size_t)r * 86 + tp] = tanhf(acc) * a2wb[tp] + a2bb[tp];
        }
        float za[6];
#pragma unroll
        for (int h = 0; h < 6; ++h) za[h] = tbl1[h * 16 + term];
#pragma unroll
        for (int i = 0; i < 24; ++i) {
            const float xv = hv[i];
#pragma unroll
            for (int h = 0; h < 6; ++h) za[h] += xv * Wl1[(h * 24 + i) * 16 + term];
        }
#pragma unroll
        for (int h = 0; h < 6; ++h) {
            float z = tanhf(za[h]);
            z1L[grp * 97 + term * 6 + h] = z;
            ps[grp * 96 + term * 6 + h] = z;
            pq[grp * 96 + term * 6 + h] = z * z;
        }
        __syncthreads();
        for (int f = tid; f < 96; f += 256) {
            float s = 0.f, q = 0.f;
#pragma unroll
            for (int g = 0; g < 16; ++g) { s += ps[g * 96 + f]; q += pq[g * 96 + f]; }
            stat_add(&st1[f], s);
            stat_add(&st1[96 + f], q);
        }
    }
    grid_barrier(bar, NBLK * 2);

    // ================= Stage L2: BN1 + aux64..79 + z2 + st2 =================
    {
        for (int j = tid; j < 96; j += 256) {
            float s = st1[j], q = st1[96 + j];
            float mu = s * invB, var = q * invB - mu * mu;
            float a = rsqrtf(var + EPSV) * bn_g[64 * 6 + j];
            int t = j / 24, i = j - t * 24;
            aAb[i * 4 + t] = a;
            aCb[i * 4 + t] = bn_b[64 * 6 + j] - mu * a;
        }
        for (int idx = tid; idx < 96; idx += 256) {
            int t = idx / 6, h = idx - t * 6;
            a1wb[h * 16 + t] = a1W[(64 + t) * 6 + h];
        }
        if (tid < 16) { a1bb[tid] = a1b[64 + tid]; a2wb[tid] = a2W[64 + tid]; a2bb[tid] = a2b[64 + tid]; }
        __syncthreads();

        const int term = tid & 3, row = tid >> 2;     // rows 0..63, 16 valid
        if (row < 16) {
            const int r = rbase + row;
            float hv[24];
#pragma unroll
            for (int i = 0; i < 24; ++i)
                hv[i] = z1L[row * 97 + term * 24 + i] * aAb[i * 4 + term] + aCb[i * 4 + term];
#pragma unroll
            for (int s = 0; s < 4; ++s) {
                const int tp = term * 4 + s;
                float acc = a1bb[tp];
#pragma unroll
                for (int h2 = 0; h2 < 6; ++h2) acc += hv[s * 6 + h2] * a1wb[h2 * 16 + tp];
                out[(size_t)r * 86 + 64 + tp] = tanhf(acc) * a2wb[tp] + a2bb[tp];
            }
            float za[6];
#pragma unroll
            for (int h = 0; h < 6; ++h) za[h] = tbl2[h * 4 + term];
#pragma unroll
            for (int i = 0; i < 24; ++i) {
                const float xv = hv[i];
#pragma unroll
                for (int h = 0; h < 6; ++h) za[h] += xv * Wl2[(h * 24 + i) * 4 + term];
            }
#pragma unroll
            for (int h = 0; h < 6; ++h) {
                float z = tanhf(za[h]);
                z2L[row * 25 + term * 6 + h] = z;
                ps[row * 24 + term * 6 + h] = z;
                pq[row * 24 + term * 6 + h] = z * z;
            }
        }
        __syncthreads();
        if (tid < 24) {
            float s = 0.f, q = 0.f;
#pragma unroll
            for (int g = 0; g < 16; ++g) { s += ps[g * 24 + tid]; q += pq[g * 24 + tid]; }
            stat_add(&st2[tid], s);
            stat_add(&st2[24 + tid], q);
        }
    }
    grid_barrier(bar, NBLK * 3);

    // ================= Stage L3: BN2 + aux80..83 + z3 + st3 =================
    {
        if (tid < 24) {
            float s = st2[tid], q = st2[24 + tid];
            float mu = s * invB, var = q * invB - mu * mu;
            float a = rsqrtf(var + EPSV) * bn_g[80 * 6 + tid];
            aAb[tid] = a;
            aCb[tid] = bn_b[80 * 6 + tid] - mu * a;
        }
        if (tid < 24) { int t = tid / 6, h = tid - t * 6; a1wb[h * 4 + t] = a1W[(80 + t) * 6 + h]; }
        if (tid < 4) { a1bb[tid] = a1b[80 + tid]; a2wb[tid] = a2W[80 + tid]; a2bb[tid] = a2b[80 + tid]; }
        __syncthreads();

        const int row = tid;                          // 16 valid
        if (row < 16) {
            const int r = rbase + row;
            float hv[24];
#pragma unroll
            for (int i = 0; i < 24; ++i)
                hv[i] = z2L[row * 25 + i] * aAb[i] + aCb[i];
#pragma unroll
            for (int s = 0; s < 4; ++s) {
                float acc = a1bb[s];
#pragma unroll
                for (int h2 = 0; h2 < 6; ++h2) acc += hv[s * 6 + h2] * a1wb[h2 * 4 + s];
                out[(size_t)r * 86 + 80 + s] = tanhf(acc) * a2wb[s] + a2bb[s];
            }
            float za[6];
#pragma unroll
            for (int h = 0; h < 6; ++h) za[h] = tbl3[h];
#pragma unroll
            for (int i = 0; i < 24; ++i) {
                const float xv = hv[i];
#pragma unroll
                for (int h = 0; h < 6; ++h) za[h] += xv * Wl3[h * 24 + i];
            }
#pragma unroll
            for (int h = 0; h < 6; ++h) {
                float z = tanhf(za[h]);
                z3L[row * 7 + h] = z;
                ps[row * 6 + h] = z;
                pq[row * 6 + h] = z * z;
            }
        }
        __syncthreads();
        if (tid < 6) {
            float s = 0.f, q = 0.f;
#pragma unroll
            for (int g = 0; g < 16; ++g) { s += ps[g * 6 + tid]; q += pq[g * 6 + tid]; }
            stat_add(&st3[tid], s);
            stat_add(&st3[6 + tid], q);
        }
    }
    grid_barrier(bar, NBLK * 4);

    // ================= Final pass 1: BN3 + aux84 + f + fstat =================
    {
        if (tid < 12) r12[tid] = st3[tid];
        __syncthreads();
        if (tid < 6) {
            float mu = r12[tid] * invB, var = r12[6 + tid] * invB - mu * mu;
            float a = rsqrtf(var + EPSV) * bn_g[84 * 6 + tid];
            a3L[tid] = a;
            c3L[tid] = bn_b[84 * 6 + tid] - mu * a;
        }
        __syncthreads();
        const int row = tid;
        if (row < 16) {
            const int r = rbase + row;
            float h[6];
#pragma unroll
            for (int j = 0; j < 6; ++j) h[j] = z3L[row * 7 + j] * a3L[j] + c3L[j];
            float acc = a1b[84];
#pragma unroll
            for (int j = 0; j < 6; ++j) acc += h[j] * a1W[84 * 6 + j];
            out[(size_t)r * 86 + 84] = tanhf(acc) * a2W[84] + a2b[84];
#pragma unroll
            for (int j = 0; j < 6; ++j) {
                float s = fb[j];
#pragma unroll
                for (int k = 0; k < 6; ++k) s += h[k] * fW[j * 6 + k];
                float f = tanhf(s);
                fL[row * 6 + j] = f;
                ps[row * 6 + j] = f;
                pq[row * 6 + j] = f * f;
            }
        }
        __syncthreads();
        if (tid < 6) {
            float s = 0.f, q = 0.f;
#pragma unroll
            for (int g = 0; g < 16; ++g) { s += ps[g * 6 + tid]; q += pq[g * 6 + tid]; }
            stat_add(&fst[tid], s);
            stat_add(&fst[6 + tid], q);
        }
    }
    grid_barrier(bar, NBLK * 5);

    // ================= Final pass 2: fbn + pred (col 85) =================
    {
        if (tid < 12) r12[tid] = fst[tid];
        __syncthreads();
        if (tid < 6) {
            float mu = r12[tid] * invB, var = r12[6 + tid] * invB - mu * mu;
            float a = rsqrtf(var + EPSV) * fbn_g[tid];
            avL[tid] = a;
            cvL[tid] = fbn_b[tid] - mu * a;
        }
        __syncthreads();
        const int row = tid;
        if (row < 16) {
            const int r = rbase + row;
            float acc = fxb[0];
#pragma unroll
            for (int j = 0; j < 6; ++j)
                acc += (fL[row * 6 + j] * avL[j] + cvL[j]) * fxW[j];
            float pre = tanhf(acc) * foW[0] + fob[0];
            out[(size_t)r * 86 + 85] = 1.0f / (1.0f + expf(-pre));
        }
    }
}

// ---------------------------------------------------------------------------
extern "C" void kernel_launch(void* const* d_in, const int* in_sizes, int n_in,
                              void* d_out, int out_size, void* d_ws, size_t ws_size,
                              hipStream_t stream)
{
    const float* x      = (const float*)d_in[0];
    const float* gene_W = (const float*)d_in[1];
    const float* gene_b = (const float*)d_in[2];
    const float* term_W = (const float*)d_in[3];
    const float* term_b = (const float*)d_in[4];
    const float* bn_g   = (const float*)d_in[5];
    const float* bn_b   = (const float*)d_in[6];
    const float* a1W    = (const float*)d_in[7];
    const float* a1b    = (const float*)d_in[8];
    const float* a2W    = (const float*)d_in[9];
    const float* a2b    = (const float*)d_in[10];
    const float* fW     = (const float*)d_in[11];
    const float* fb     = (const float*)d_in[12];
    const float* fbn_g  = (const float*)d_in[13];
    const float* fbn_b  = (const float*)d_in[14];
    const float* fxW    = (const float*)d_in[15];
    const float* fxb    = (const float*)d_in[16];
    const float* foW    = (const float*)d_in[17];
    const float* fob    = (const float*)d_in[18];
    float* out = (float*)d_out;

    const size_t XB  = 33554432;   // x bf16
    const size_t WBS = 12582912;   // gene_W bf16
    const size_t P0  = 25165824;   // f32 partial
    const size_t P1B = 12582912;   // bf16 partial

    char* ws = (char*)d_ws;
    uint16_t* xbuf = (uint16_t*)ws;
    uint16_t* wbuf = (uint16_t*)(ws + XB);
    float*    p0   = (float*)(ws + XB + WBS);
    uint16_t* p1b  = (uint16_t*)(ws + XB + WBS + P0);
    float*    stats = (float*)(ws + XB + WBS + P0 + P1B);  // 1040 f32

    cvt_bf16<<<11264, 256, 0, stream>>>(x, gene_W, xbuf, wbuf, stats);
    gemm_glds<<<dim3(12, 32, 2), 256, 0, stream>>>(xbuf, wbuf, gene_b, p0, p1b, GDIM / 2);
    tail_fused<<<NBLK, 256, 0, stream>>>(
        p0, p1b, term_W, term_b, bn_g, bn_b, a1W, a1b, a2W, a2b,
        fW, fb, fbn_g, fbn_b, fxW, fxb, foW, fob, stats, out);
}

// Round 8
// 244.655 us; speedup vs baseline: 1.3943x; 1.3109x over previous
//
#include <hip/hip_runtime.h>
#include <stdint.h>
#include <math.h>

#define EPSV   1e-5f
#define BATCH  4096
#define GDIM   4096
#define NF0    384     // folded level-0 output features (64 terms * 6)
#define NSPLIT 8       // GEMM split-K factor

typedef __attribute__((ext_vector_type(8))) short bf16x8;
typedef __attribute__((ext_vector_type(4))) float f32x4;
typedef __attribute__((ext_vector_type(4))) uint32_t u32x4;

__device__ __forceinline__ uint32_t pkbf(float x, float y) {
    uint32_t a = __float_as_uint(x) + 0x8000u;
    uint32_t b = __float_as_uint(y) + 0x8000u;
    return __builtin_amdgcn_perm(b, a, 0x07060302u);
}
__device__ __forceinline__ uint16_t f2bf(float f) {
    return (uint16_t)((__float_as_uint(f) + 0x8000u) >> 16);
}
__device__ __forceinline__ float bf2f(uint16_t u) {
    union { uint32_t u; float f; } v; v.u = ((uint32_t)u) << 16; return v.f;
}
__device__ __forceinline__ void glds16(const uint16_t* g, short* l) {
    __builtin_amdgcn_global_load_lds(
        (const __attribute__((address_space(1))) void*)g,
        (__attribute__((address_space(3))) void*)l, 16, 0, 0);
}

// ---------------------------------------------------------------------------
// prep: blocks [0,8192): convert x f32->bf16 (8 elems/thread).
//       blocks [8192,9216): fold M0[t*6+h][g] = sum_i term_W[t,h,i]*gene_W[t,i,g]
//       block 0 also zeroes stats.
// ---------------------------------------------------------------------------
__global__ __launch_bounds__(256) void prep_kernel(
    const float* __restrict__ x, const float* __restrict__ gene_W,
    const float* __restrict__ term_W,
    uint16_t* __restrict__ xb, uint16_t* __restrict__ m0,
    float* __restrict__ stats)
{
    const int tid = threadIdx.x;
    if (blockIdx.x == 0)
        for (int j = tid; j < 1040; j += 256) stats[j] = 0.f;
    if (blockIdx.x < 8192) {
        size_t i = (size_t)blockIdx.x * 256 + tid;
        const float* src = x + i * 8;
        f32x4 v0 = *(const f32x4*)src;
        f32x4 v1 = *(const f32x4*)(src + 4);
        u32x4 p = (u32x4){pkbf(v0[0],v0[1]), pkbf(v0[2],v0[3]),
                          pkbf(v1[0],v1[1]), pkbf(v1[2],v1[3])};
        *(u32x4*)(xb + i * 8) = p;
    } else {
        __shared__ float Wl[144];
        const int bid = blockIdx.x - 8192;        // 0..1023
        const int t = bid >> 4;                   // term 0..63
        const int g = ((bid & 15) << 8) + tid;    // gene 0..4095
        if (tid < 144) Wl[tid] = term_W[t * 144 + tid];
        __syncthreads();
        float gw[24];
#pragma unroll
        for (int i = 0; i < 24; ++i)
            gw[i] = gene_W[((size_t)t * 24 + i) * GDIM + g];
#pragma unroll
        for (int h = 0; h < 6; ++h) {
            float s = 0.f;
#pragma unroll
            for (int i = 0; i < 24; ++i) s += Wl[h * 24 + i] * gw[i];
            m0[((size_t)(t * 6 + h)) * GDIM + g] = f2bf(s);
        }
    }
}

// ---------------------------------------------------------------------------
// m97-style GEMM: C[4096, 384] partials (bf16), split-K=8 over blockIdx.z.
// 128x128 tile, BK=32, glds16 staging, 4 waves, 4x4 mfma 16x16x32 per wave.
// ---------------------------------------------------------------------------
__global__ __launch_bounds__(256) void gemm_glds(
    const uint16_t* __restrict__ A, const uint16_t* __restrict__ Bw,
    uint16_t* __restrict__ P, int KC)
{
    const int N = NF0, K = GDIM;
    __shared__ short sA[128 * 32];
    __shared__ short sB[128 * 32];
    const int tid  = threadIdx.x;
    const int m0   = blockIdx.y * 128, n0 = blockIdx.x * 128;
    const int kbase = blockIdx.z * KC;
    uint16_t* Cp = P + (size_t)blockIdx.z * ((size_t)BATCH * NF0);
    const int wave = tid >> 6, lane = tid & 63;
    const int wm   = (wave & 1) << 6, wn = (wave >> 1) << 6;
    const int lm   = lane & 15, quad = lane >> 4;

    f32x4 acc[4][4];
#pragma unroll
    for (int i = 0; i < 4; ++i)
#pragma unroll
        for (int j = 0; j < 4; ++j) acc[i][j] = (f32x4){0.f, 0.f, 0.f, 0.f};

    const int r0  = tid >> 2;
    const int c0e = (tid & 3) << 3;
    const uint16_t* gA = A  + (size_t)(m0 + r0) * K + kbase + c0e;
    const uint16_t* gB = Bw + (size_t)(n0 + r0) * K + kbase + c0e;
    short* la0 = &sA[tid * 8];
    short* la1 = &sA[2048 + tid * 8];
    short* lb0 = &sB[tid * 8];
    short* lb1 = &sB[2048 + tid * 8];
    const size_t rowskip = (size_t)64 * K;

    for (int k0 = 0; k0 < KC; k0 += 32) {
        __syncthreads();
        glds16(gA + k0,            la0);
        glds16(gA + rowskip + k0,  la1);
        glds16(gB + k0,            lb0);
        glds16(gB + rowskip + k0,  lb1);
        __syncthreads();
        bf16x8 af[4], bfr[4];
#pragma unroll
        for (int m = 0; m < 4; ++m)
            af[m]  = *(const bf16x8*)&sA[(wm + m * 16 + lm) * 32 + quad * 8];
#pragma unroll
        for (int n = 0; n < 4; ++n)
            bfr[n] = *(const bf16x8*)&sB[(wn + n * 16 + lm) * 32 + quad * 8];
#pragma unroll
        for (int m = 0; m < 4; ++m)
#pragma unroll
            for (int n = 0; n < 4; ++n)
                acc[m][n] = __builtin_amdgcn_mfma_f32_16x16x32_bf16(
                    af[m], bfr[n], acc[m][n], 0, 0, 0);
    }
    // C/D layout: col = lane&15, row = quad*4 + reg
#pragma unroll
    for (int n = 0; n < 4; ++n) {
        const int col = n0 + wn + n * 16 + lm;
#pragma unroll
        for (int m = 0; m < 4; ++m) {
            const int row = m0 + wm + m * 16 + (quad << 2);
            uint16_t* cp = Cp + (size_t)row * N + col;
#pragma unroll
            for (int r = 0; r < 4; ++r) cp[(size_t)r * N] = f2bf(acc[m][n][r]);
        }
    }
}

// ---------------------------------------------------------------------------
// lzero: z0 = tanh(sum_z P[z] + bias0), bias0[f] = sum_i W0[t,h,i]*gene_b[t,i]
// + term_b[t,h]  (f = t*6+h). Also st0 (sum/sumsq per feature).
// 256 blocks x 384 threads; thread = feature, 16 rows/block.
// ---------------------------------------------------------------------------
__global__ __launch_bounds__(384) void lzero_kernel(
    const uint16_t* __restrict__ P, const float* __restrict__ term_W,
    const float* __restrict__ term_b, const float* __restrict__ gene_b,
    float* __restrict__ z0, float* __restrict__ st0)
{
    const int f = threadIdx.x;            // 0..383
    const int t = f / 6, h = f - t * 6;
    const int rbase = blockIdx.x * 16;
    float bias = term_b[t * 6 + h];
#pragma unroll
    for (int i = 0; i < 24; ++i)
        bias += term_W[t * 144 + h * 24 + i] * gene_b[t * 24 + i];
    float s = 0.f, q = 0.f;
    for (int rl = 0; rl < 16; ++rl) {
        const size_t r = rbase + rl;
        float acc = bias;
#pragma unroll
        for (int z = 0; z < NSPLIT; ++z)
            acc += bf2f(P[(size_t)z * BATCH * NF0 + r * NF0 + f]);
        float zv = tanhf(acc);
        z0[r * NF0 + f] = zv;
        s += zv; q += zv * zv;
    }
    atomicAdd(&st0[f], s);
    atomicAdd(&st0[NF0 + f], q);
}

// ---------------------------------------------------------------------------
// Level kernel (R4-proven). Reads 'in' (B x 24N), normalizes with stats_prev,
// emits prev-level aux cols, computes z = tanh(.) + stats.
// ---------------------------------------------------------------------------
template <int N, int ROWS, int OFF, int PREV_OFF>
__global__ __launch_bounds__(256) void level_kernel(
    const float* __restrict__ in, float* __restrict__ z_out,
    const float* __restrict__ stats_prev, float* __restrict__ stats_out,
    const float* __restrict__ term_W, const float* __restrict__ term_b,
    const float* __restrict__ bn_gamma, const float* __restrict__ bn_beta,
    const float* __restrict__ aux1_W, const float* __restrict__ aux1_b,
    const float* __restrict__ aux2_W, const float* __restrict__ aux2_b,
    float* __restrict__ out)
{
    constexpr int IN_W  = 24 * N;
    constexpr int NFv   = 6 * N;
    constexpr int NG    = 256 / N;
    constexpr int ITERS = (ROWS * N) / 256;
    constexpr int NPREV = 4 * N;

    __shared__ float Wl[144 * N];
    __shared__ float tbl[6 * N];
    __shared__ float aA[IN_W];
    __shared__ float aC[IN_W];
    __shared__ float a1wL[6 * NPREV];
    __shared__ float a1bL[NPREV], a2wL[NPREV], a2bL[NPREV];
    __shared__ float ps[NG * NFv], pq[NG * NFv];

    const int tid = threadIdx.x;
    for (int idx = tid; idx < 144 * N; idx += 256) {
        int t = idx / 144, fh = idx - t * 144;
        Wl[fh * N + t] = term_W[(OFF + t) * 144 + fh];
    }
    for (int idx = tid; idx < 6 * N; idx += 256) {
        int t = idx / 6, h = idx - t * 6;
        tbl[h * N + t] = term_b[(OFF + t) * 6 + h];
    }
    {
        const float invB = 1.0f / BATCH;
        for (int j = tid; j < IN_W; j += 256) {
            float s = stats_prev[j], q = stats_prev[IN_W + j];
            float mu = s * invB;
            float var = q * invB - mu * mu;
            float rstd = rsqrtf(var + EPSV);
            float a = rstd * bn_gamma[PREV_OFF * 6 + j];
            int t = j / 24, i = j - t * 24;
            aA[i * N + t] = a;
            aC[i * N + t] = bn_beta[PREV_OFF * 6 + j] - mu * a;
        }
        for (int idx = tid; idx < 6 * NPREV; idx += 256) {
            int t = idx / 6, h = idx - t * 6;
            a1wL[h * NPREV + t] = aux1_W[(PREV_OFF + t) * 6 + h];
        }
        for (int t = tid; t < NPREV; t += 256) {
            a1bL[t] = aux1_b[PREV_OFF + t];
            a2wL[t] = aux2_W[PREV_OFF + t];
            a2bL[t] = aux2_b[PREV_OFF + t];
        }
    }
    __syncthreads();

    const int term = tid & (N - 1);
    const int grp  = tid / N;
    float s6[6], q6[6];
#pragma unroll
    for (int h = 0; h < 6; ++h) { s6[h] = 0.f; q6[h] = 0.f; }

    for (int it = 0; it < ITERS; ++it) {
        const int r = blockIdx.x * ROWS + it * NG + grp;
        const float* inrow = in + (size_t)r * IN_W + term * 24;
        float hv[24];
#pragma unroll
        for (int i4 = 0; i4 < 6; ++i4) {
            f32x4 v = *(const f32x4*)(inrow + 4 * i4);
            hv[4*i4+0] = v[0]; hv[4*i4+1] = v[1];
            hv[4*i4+2] = v[2]; hv[4*i4+3] = v[3];
        }
#pragma unroll
        for (int i = 0; i < 24; ++i)
            hv[i] = hv[i] * aA[i * N + term] + aC[i * N + term];
#pragma unroll
        for (int s = 0; s < 4; ++s) {
            const int tp = term * 4 + s;
            float acc = a1bL[tp];
#pragma unroll
            for (int h2 = 0; h2 < 6; ++h2) acc += hv[s * 6 + h2] * a1wL[h2 * NPREV + tp];
            float a1 = tanhf(acc);
            out[(size_t)r * 86 + PREV_OFF + tp] = a1 * a2wL[tp] + a2bL[tp];
        }
        float za[6];
#pragma unroll
        for (int h = 0; h < 6; ++h) za[h] = tbl[h * N + term];
#pragma unroll
        for (int i = 0; i < 24; ++i) {
            const float x = hv[i];
#pragma unroll
            for (int h = 0; h < 6; ++h) za[h] += x * Wl[(h * 24 + i) * N + term];
        }
        float* zr = z_out + (size_t)r * NFv + term * 6;
#pragma unroll
        for (int h = 0; h < 6; ++h) {
            float z = tanhf(za[h]);
            zr[h] = z;
            s6[h] += z;
            q6[h] += z * z;
        }
    }
#pragma unroll
    for (int h = 0; h < 6; ++h) {
        ps[grp * NFv + term * 6 + h] = s6[h];
        pq[grp * NFv + term * 6 + h] = q6[h];
    }
    __syncthreads();
    for (int f = tid; f < NFv; f += 256) {
        float s = 0.f, q = 0.f;
        for (int g2 = 0; g2 < NG; ++g2) { s += ps[g2 * NFv + f]; q += pq[g2 * NFv + f]; }
        atomicAdd(&stats_out[f], s);
        atomicAdd(&stats_out[NFv + f], q);
    }
}

// ---------------------------------------------------------------------------
// Fused final stage (R4-proven): one block, 1024 threads, 4 rows/thread.
// ---------------------------------------------------------------------------
__global__ __launch_bounds__(1024) void final_fused(
    const float* __restrict__ z3, const float* __restrict__ st3,
    const float* __restrict__ bn_gamma, const float* __restrict__ bn_beta,
    const float* __restrict__ aux1_W, const float* __restrict__ aux1_b,
    const float* __restrict__ aux2_W, const float* __restrict__ aux2_b,
    const float* __restrict__ final_W, const float* __restrict__ final_b,
    const float* __restrict__ fbn_gamma, const float* __restrict__ fbn_beta,
    const float* __restrict__ faux_W, const float* __restrict__ faux_b,
    const float* __restrict__ fout_W, const float* __restrict__ fout_b,
    float* __restrict__ out)
{
    __shared__ float wred[16][12];
    __shared__ float fstat[12];
    const int tid = threadIdx.x;
    const float invB = 1.0f / BATCH;
    float a[6], c[6], fw[36], fbv[6];
#pragma unroll
    for (int j = 0; j < 6; ++j) {
        float s = st3[j], q = st3[6 + j];
        float mu = s * invB, var = q * invB - mu * mu;
        float rstd = rsqrtf(var + EPSV);
        a[j] = rstd * bn_gamma[84 * 6 + j];
        c[j] = bn_beta[84 * 6 + j] - mu * a[j];
        fbv[j] = final_b[j];
    }
#pragma unroll
    for (int j = 0; j < 36; ++j) fw[j] = final_W[j];

    float s6[6], q6[6];
#pragma unroll
    for (int j = 0; j < 6; ++j) { s6[j] = 0.f; q6[j] = 0.f; }

    for (int i = 0; i < 4; ++i) {
        const int r = i * 1024 + tid;
        float h[6];
#pragma unroll
        for (int j = 0; j < 6; ++j) h[j] = z3[(size_t)r * 6 + j] * a[j] + c[j];
        float acc = aux1_b[84];
#pragma unroll
        for (int j = 0; j < 6; ++j) acc += h[j] * aux1_W[84 * 6 + j];
        out[(size_t)r * 86 + 84] = tanhf(acc) * aux2_W[84] + aux2_b[84];
#pragma unroll
        for (int j = 0; j < 6; ++j) {
            float s = fbv[j];
#pragma unroll
            for (int k = 0; k < 6; ++k) s += h[k] * fw[j * 6 + k];
            float f = tanhf(s);
            s6[j] += f; q6[j] += f * f;
        }
    }
#pragma unroll
    for (int off = 32; off >= 1; off >>= 1) {
#pragma unroll
        for (int j = 0; j < 6; ++j) {
            s6[j] += __shfl_xor(s6[j], off, 64);
            q6[j] += __shfl_xor(q6[j], off, 64);
        }
    }
    const int wv = tid >> 6, ln = tid & 63;
    if (ln == 0) {
#pragma unroll
        for (int j = 0; j < 6; ++j) { wred[wv][j] = s6[j]; wred[wv][6 + j] = q6[j]; }
    }
    __syncthreads();
    if (tid < 12) {
        float s = 0.f;
#pragma unroll
        for (int w = 0; w < 16; ++w) s += wred[w][tid];
        fstat[tid] = s;
    }
    __syncthreads();
    float av[6], cv[6];
#pragma unroll
    for (int j = 0; j < 6; ++j) {
        float mu = fstat[j] * invB, var = fstat[6 + j] * invB - mu * mu;
        float rstd = rsqrtf(var + EPSV);
        av[j] = rstd * fbn_gamma[j];
        cv[j] = fbn_beta[j] - mu * av[j];
    }
    const float fxb0 = faux_b[0], foW0 = fout_W[0], fob0 = fout_b[0];
    for (int i = 0; i < 4; ++i) {
        const int r = i * 1024 + tid;
        float h[6];
#pragma unroll
        for (int j = 0; j < 6; ++j) h[j] = z3[(size_t)r * 6 + j] * a[j] + c[j];
        float acc2 = fxb0;
#pragma unroll
        for (int j = 0; j < 6; ++j) {
            float s = fbv[j];
#pragma unroll
            for (int k = 0; k < 6; ++k) s += h[k] * fw[j * 6 + k];
            float fn = tanhf(s) * av[j] + cv[j];
            acc2 += fn * faux_W[j];
        }
        float fa  = tanhf(acc2);
        float pre = fa * foW0 + fob0;
        out[(size_t)r * 86 + 85] = 1.0f / (1.0f + expf(-pre));
    }
}

// ---------------------------------------------------------------------------
extern "C" void kernel_launch(void* const* d_in, const int* in_sizes, int n_in,
                              void* d_out, int out_size, void* d_ws, size_t ws_size,
                              hipStream_t stream)
{
    const float* x      = (const float*)d_in[0];
    const float* gene_W = (const float*)d_in[1];
    const float* gene_b = (const float*)d_in[2];
    const float* term_W = (const float*)d_in[3];
    const float* term_b = (const float*)d_in[4];
    const float* bn_g   = (const float*)d_in[5];
    const float* bn_b   = (const float*)d_in[6];
    const float* a1W    = (const float*)d_in[7];
    const float* a1b    = (const float*)d_in[8];
    const float* a2W    = (const float*)d_in[9];
    const float* a2b    = (const float*)d_in[10];
    const float* fW     = (const float*)d_in[11];
    const float* fb     = (const float*)d_in[12];
    const float* fbn_g  = (const float*)d_in[13];
    const float* fbn_b  = (const float*)d_in[14];
    const float* fxW    = (const float*)d_in[15];
    const float* fxb    = (const float*)d_in[16];
    const float* foW    = (const float*)d_in[17];
    const float* fob    = (const float*)d_in[18];
    float* out = (float*)d_out;

    const size_t XB  = 33554432;                          // x bf16
    const size_t M0B = (size_t)NF0 * GDIM * 2;            // 3,145,728
    const size_t PB  = (size_t)NSPLIT * BATCH * NF0 * 2;  // 25,165,824
    const size_t Z0B = (size_t)BATCH * NF0 * 4;           // 6,291,456

    char* ws = (char*)d_ws;
    uint16_t* xbuf = (uint16_t*)ws;
    uint16_t* m0b  = (uint16_t*)(ws + XB);
    uint16_t* pbuf = (uint16_t*)(ws + XB + M0B);
    float*    z0   = (float*)(ws + XB + M0B + PB);
    float*    z1   = (float*)(ws + XB + M0B + PB + Z0B);
    float*    z2   = (float*)(ws + XB + M0B + PB + Z0B + 1572864);
    float*    z3   = (float*)(ws + XB + M0B + PB + Z0B + 1572864 + 393216);
    float*    stats = (float*)(ws + XB + M0B + PB + Z0B + 1572864 + 393216 + 98304);
    float* st0 = stats;         // 384+384
    float* st1 = stats + 768;   // 96+96
    float* st2 = stats + 960;   // 24+24
    float* st3 = stats + 1008;  // 6+6

    prep_kernel<<<9216, 256, 0, stream>>>(x, gene_W, term_W, xbuf, m0b, stats);
    gemm_glds<<<dim3(3, 32, NSPLIT), 256, 0, stream>>>(xbuf, m0b, pbuf, GDIM / NSPLIT);
    lzero_kernel<<<256, 384, 0, stream>>>(pbuf, term_W, term_b, gene_b, z0, st0);
    level_kernel<16, 16, 64, 0><<<256, 256, 0, stream>>>(
        z0, z1, st0, st1, term_W, term_b, bn_g, bn_b, a1W, a1b, a2W, a2b, out);
    level_kernel<4, 64, 80, 64><<<64, 256, 0, stream>>>(
        z1, z2, st1, st2, term_W, term_b, bn_g, bn_b, a1W, a1b, a2W, a2b, out);
    level_kernel<1, 256, 84, 80><<<16, 256, 0, stream>>>(
        z2, z3, st2, st3, term_W, term_b, bn_g, bn_b, a1W, a1b, a2W, a2b, out);
    final_fused<<<1, 1024, 0, stream>>>(
        z3, st3, bn_g, bn_b, a1W, a1b, a2W, a2b, fW, fb,
        fbn_g, fbn_b, fxW, fxb, foW, fob, out);
}